// Round 8
// baseline (1340.489 us; speedup 1.0000x reference)
//
#include <hip/hip_runtime.h>

typedef unsigned int u32;
typedef unsigned short u16;
typedef unsigned char u8;
typedef unsigned long long u64;
typedef __attribute__((ext_vector_type(8))) short short8;
typedef __attribute__((ext_vector_type(4))) float floatx4;
typedef __attribute__((ext_vector_type(4))) int intx4;

#define TT 1024
#define BIN_OFF 6553600
#define ACT_OFF 7864320

__device__ __forceinline__ u16 f2b(float f) {
  u32 u = __builtin_bit_cast(u32, f);
  u += 0x7fffu + ((u >> 16) & 1u);
  return (u16)(u >> 16);
}
__device__ __forceinline__ float sigmf(float x) { return 1.0f / (1.0f + __expf(-x)); }

// ---------------- prep ----------------

__global__ void k_zero4(u32* __restrict__ p) {
  if (threadIdx.x < 4) p[threadIdx.x] = 0;
}
// absmax of x / W_hh / W_ih -> am[0..2].  grid 2048 x 256
__global__ void k_amax(const float* __restrict__ x, const float* __restrict__ wih,
                       const float* __restrict__ whh, u32* __restrict__ am) {
  __shared__ float red[256];
  const int tid = threadIdx.x;
  int b = blockIdx.x;
  const float* src; size_t n; int sec, b0, nb;
  if (b < 1920)      { src = x;   n = 5636096; sec = 0; b0 = 0;    nb = 1920; }
  else if (b < 2016) { src = whh; n = 262144;  sec = 1; b0 = 1920; nb = 96; }
  else               { src = wih; n = 44032;   sec = 2; b0 = 2016; nb = 32; }
  float m = 0.f;
  for (size_t i = (size_t)(b - b0) * 256 + tid; i < n; i += (size_t)nb * 256)
    m = fmaxf(m, fabsf(src[i]));
  red[tid] = m;
  __syncthreads();
  for (int s = 128; s > 0; s >>= 1) {
    if (tid < s) red[tid] = fmaxf(red[tid], red[tid + s]);
    __syncthreads();
  }
  if (tid == 0) atomicMax(&am[sec], __float_as_uint(red[0]));
}
// bias = b_ih + b_hh.  grid 4 x 256
__global__ void k_prep_bias(const float* __restrict__ a, const float* __restrict__ b,
                            float* __restrict__ o) {
  int i = blockIdx.x * 256 + threadIdx.x;
  o[i] = a[i] + b[i];
}
// i8 weight frags. Per wave w: 40 frags, F = tile*5 + c (tile = gate*2+ht;
// c 0..3 h-chunks scale sn_h, c=4 x-chunk scale sn_x, with bias codes at
// k=43 (coarse, unit 127*A_x) and k=44 (fine, unit 127*A_h)).
// A-frag lane l: n = gate*256+w*32+ht*16+(l&15); k = (l>>4)*16 + jq*4 + b.
// grid 320 x 256
__global__ void k_prep_wq2(const float* __restrict__ wih, const float* __restrict__ whh,
                           const float* __restrict__ bias, const u32* __restrict__ am,
                           int* __restrict__ wq, float* __restrict__ sbuf) {
  u32 idx = blockIdx.x * 256 + threadIdx.x;
  const float xmax = fmaxf(__uint_as_float(am[0]), 1e-8f);
  const float whm  = fmaxf(__uint_as_float(am[1]), 1e-8f);
  const float wxm  = fmaxf(__uint_as_float(am[2]), 1e-8f);
  const float sn_h = whm / 127.0f, sn_x = wxm / 127.0f;
  const float sx = xmax / 127.0f;
  const float A_h = sn_h / 127.0f;          // unit of wh_int*h_int and of x-res path
  const float A_x = sn_x * sx;              // unit of wx_int*x_int
  if (idx == 0) { sbuf[0] = A_h; sbuf[1] = A_x; }
  int jq = idx & 3;
  int lane = (idx >> 2) & 63;
  u32 wf = idx >> 8;                        // w*40 + F, < 320
  int F = wf % 40, w = wf / 40;
  int tile = F / 5, c = F % 5;
  int gate = tile >> 1, ht = tile & 1;
  int l15 = lane & 15, kq = lane >> 4;
  int n = gate * 256 + w * 32 + ht * 16 + l15;
  u32 out = 0;
#pragma unroll
  for (int b = 0; b < 4; ++b) {
    int kl = kq * 16 + jq * 4 + b;
    float q = 0.f;
    if (c < 4) {
      q = rintf(whh[n * 256 + c * 64 + kl] / sn_h);
    } else {
      if (kl < 43) q = rintf(wih[n * 43 + kl] / sn_x);
      else if (kl == 43) {
        q = fminf(fmaxf(rintf(bias[n] / (127.0f * A_x)), -127.f), 127.f);
      } else if (kl == 44) {
        float qc = fminf(fmaxf(rintf(bias[n] / (127.0f * A_x)), -127.f), 127.f);
        q = rintf((bias[n] - qc * 127.0f * A_x) / (127.0f * A_h));
      }
    }
    q = fminf(fmaxf(q, -127.f), 127.f);
    int qi = (int)q;
    out |= ((u32)(qi & 255)) << (8 * b);
  }
  wq[idx] = (int)out;
}
// chunk-packed i8 x-image B-frags (full 16-slot M!):
// per (bg, mt, res) one 1KB unit, unit index = bg*256 + mt*2 + res.
// unit byte[m*64 + k]: m = tloc*2 + r (t = mt*8 + tloc, row = bg*2 + r).
// k<35: x[row][t][k]; 35..42: x[row][t-1][k]; 43: main 127 / res 0 (bias
// coarse slot); 44: main 0 / res 127 (bias fine slot); 45..63: 0.
// main scale sx, residual scale sr = A_h/sn_x.
// grid 16384 x 256
__global__ void k_prep_xq2(const float* __restrict__ x, const u32* __restrict__ am,
                           int* __restrict__ xq) {
  u32 idx = blockIdx.x * 256 + threadIdx.x;
  const float xmax = fmaxf(__uint_as_float(am[0]), 1e-8f);
  const float whm  = fmaxf(__uint_as_float(am[1]), 1e-8f);
  const float wxm  = fmaxf(__uint_as_float(am[2]), 1e-8f);
  const float sx = xmax / 127.0f;
  const float sr = whm / (127.0f * wxm);    // A_h / sn_x
  u32 unit = idx >> 8;                      // bg*256 + mt*2 + res
  u32 dwIn = idx & 255;
  int lane = dwIn >> 2, reg = dwIn & 3;
  int m = lane & 15, kq = lane >> 4;
  int bg = unit >> 8;
  int rem = unit & 255;
  int mt = rem >> 1, res = rem & 1;
  int t = mt * 8 + (m >> 1);
  int row = bg * 2 + (m & 1);
  u32 out = 0;
#pragma unroll
  for (int b = 0; b < 4; ++b) {
    int k = kq * 16 + reg * 4 + b;
    int q = 0;
    if (k < 43) {
      float xv = 0.f;
      if (k < 35) xv = x[((size_t)row * TT + t) * 43 + k];
      else if (t > 0) xv = x[((size_t)row * TT + (t - 1)) * 43 + k];
      float q1 = fminf(fmaxf(rintf(xv / sx), -127.f), 127.f);
      if (!res) q = (int)q1;
      else q = (int)fminf(fmaxf(rintf((xv - sx * q1) / sr), -127.f), 127.f);
    } else if (k == 43) q = res ? 0 : 127;
    else if (k == 44) q = res ? 127 : 0;
    out |= ((u32)(q & 255)) << (8 * b);
  }
  xq[idx] = (int)out;
}
// W_afc1 (256x256) and W_aout padded to 16x256.  grid 272 x 256
__global__ void k_prep_afc(const float* __restrict__ wafc1, const float* __restrict__ waout,
                           u16* __restrict__ ob1, u16* __restrict__ ob2) {
  int r = blockIdx.x, k = threadIdx.x;
  if (r < 256) ob1[r * 256 + k] = f2b(wafc1[r * 256 + k]);
  else {
    int y = r - 256;
    ob2[y * 256 + k] = f2b(y < 8 ? waout[y * 256 + k] : 0.f);
  }
}
// Wcb[64][288].  grid 64 x 288
__global__ void k_prep_wcb(const float* __restrict__ wcont, const float* __restrict__ wbin,
                           u16* __restrict__ o) {
  int nrow = blockIdx.x, k = threadIdx.x;
  float v = 0.f;
  if (k < 264) {
    if (nrow < 50) v = wcont[nrow * 264 + k];
    else if (nrow < 60) v = wbin[(nrow - 50) * 264 + k];
  }
  o[nrow * 288 + k] = f2b(v);
}

// ---------------- LSTM scan v15: v14b + conflict-free gimg stride ----------------
// v14b post-mortem: SQ_LDS_BANK_CONFLICT = 1.678e7 (identical to v13) ->
// fingerprint of the GS2=264 gimg row stride: 4*264 = 1056 == 0 (mod 32),
// so the 8-lane masked ds_write_b128 folds l15=0 and l15=1 onto the SAME
// 16 banks (2-way, 16 banks idle). GS2=268: 4*268 = 1072 == 16 (mod 32) ->
// l15=1 shifted 16 banks -> 8 distinct bank-quads = all 32 banks covered,
// conflict-free (v12's 1028==4 mod 32 trick, reapplied). Reads become
// (lr*16 + g*12 + lc) mod 32: 2 lanes/bank = wave64 minimum (free).
// Everything else byte-identical to the passing v14b.
#define XS 257
#define GS2 268
#define BARX() do { \
  asm volatile("s_waitcnt lgkmcnt(0)" ::: "memory"); \
  __builtin_amdgcn_s_barrier(); \
  __builtin_amdgcn_sched_barrier(0); \
} while (0)

// phase-G half: x-main + x-res MFMAs for 4 gates of half HT, prescaled combine
template <int HT>
__device__ __forceinline__ void phaseg(const intx4 (&wfr)[40], intx4 xm, intx4 xr,
                                       floatx4* xgw, int l15, int wcol,
                                       float Sx1, float Sx2, float Ah1, float Ah2) {
  const intx4 z = {0, 0, 0, 0};
  intx4 AX[4], AR[4];
#pragma unroll
  for (int g = 0; g < 4; ++g) {
    const int F = (g * 2 + HT) * 5 + 4;
    AX[g] = __builtin_amdgcn_mfma_i32_16x16x64_i8(wfr[F], xm, z, 0, 0, 0);
    AR[g] = __builtin_amdgcn_mfma_i32_16x16x64_i8(wfr[F], xr, z, 0, 0, 0);
  }
#pragma unroll
  for (int rr = 0; rr < 4; ++rr) {
    floatx4 P;
#pragma unroll
    for (int g = 0; g < 4; ++g) {
      const float sx = (g == 2) ? Sx2 : Sx1;
      const float sh = (g == 2) ? Ah2 : Ah1;
      P[g] = fmaf(sx, (float)AX[g][rr], sh * (float)AR[g][rr]);
    }
    xgw[l15 * XS + wcol + HT * 16 + rr] = P;
  }
}

#define MCH(DST, G, HT) { \
  const int F_ = ((G) * 2 + (HT)) * 5; \
  intx4 a_ = __builtin_amdgcn_mfma_i32_16x16x64_i8(wfr[F_ + 0], bh0, z, 0, 0, 0); \
  a_ = __builtin_amdgcn_mfma_i32_16x16x64_i8(wfr[F_ + 1], bh1, a_, 0, 0, 0); \
  a_ = __builtin_amdgcn_mfma_i32_16x16x64_i8(wfr[F_ + 2], bh2, a_, 0, 0, 0); \
  DST = __builtin_amdgcn_mfma_i32_16x16x64_i8(wfr[F_ + 3], bh3, a_, 0, 0, 0); \
}

#define STEP(TL, EXTRA) do { \
  enum { CUR = (TL) & 1, NXT = CUR ^ 1 }; \
  if ((TL) == 0) { if (ch > 0) hb[-256] = h16; } \
  else hb[((TL) - 1) * 256] = h16; \
  intx4 bh0 = *(const intx4*)&bimg[CUR * 4096 + bA0]; \
  intx4 bh1 = *(const intx4*)&bimg[CUR * 4096 + bA1]; \
  intx4 bh2 = *(const intx4*)&bimg[CUR * 4096 + bA2]; \
  intx4 bh3 = *(const intx4*)&bimg[CUR * 4096 + bA3]; \
  floatx4 P = xgr[((TL) * 2 + lr) * XS + mycol]; \
  const intx4 z = {0, 0, 0, 0}; \
  intx4 A0, A1, A2, A3, A4, A5, A6, A7; \
  __builtin_amdgcn_s_setprio(1); \
  MCH(A0, 0, 0) MCH(A1, 1, 0) MCH(A2, 2, 0) MCH(A3, 3, 0) \
  MCH(A4, 0, 1) MCH(A5, 1, 1) MCH(A6, 2, 1) MCH(A7, 3, 1) \
  __builtin_amdgcn_s_setprio(0); \
  if (l15 < 2) { \
    *(intx4*)&gw[0 * GS2 +  0] = A0; *(intx4*)&gw[1 * GS2 +  0] = A1; \
    *(intx4*)&gw[2 * GS2 +  0] = A2; *(intx4*)&gw[3 * GS2 +  0] = A3; \
    *(intx4*)&gw[0 * GS2 + 16] = A4; *(intx4*)&gw[1 * GS2 + 16] = A5; \
    *(intx4*)&gw[2 * GS2 + 16] = A6; *(intx4*)&gw[3 * GS2 + 16] = A7; \
  } \
  asm volatile("s_waitcnt lgkmcnt(0)" ::: "memory"); \
  __builtin_amdgcn_sched_barrier(0); \
  { \
    float a0 = (float)gr[0 * GS2], a1 = (float)gr[1 * GS2]; \
    float a2 = (float)gr[2 * GS2], a3 = (float)gr[3 * GS2]; \
    float zz0 = fmaf(Ah1, a0, P[0]); \
    float zz1 = fmaf(Ah1, a1, P[1]); \
    float zz2 = fminf(fmaf(Ah2, a2, P[2]), 43.0f); \
    float zz3 = fmaf(Ah1, a3, P[3]); \
    float iv = __builtin_amdgcn_rcpf(1.0f + exp2f(-zz0)); \
    float fv = __builtin_amdgcn_rcpf(1.0f + exp2f(-zz1)); \
    float eg = exp2f(zz2); \
    float gv = (eg - 1.0f) * __builtin_amdgcn_rcpf(eg + 1.0f); \
    float ov = __builtin_amdgcn_rcpf(1.0f + exp2f(-zz3)); \
    float cc = fv * c_st + iv * gv; \
    c_st = cc; \
    float dd = fminf(cc * T2L2E, 43.0f); \
    float ec = exp2f(dd); \
    float th = (ec - 1.0f) * __builtin_amdgcn_rcpf(ec + 1.0f); \
    float h = ov * th; \
    bimg[NXT * 4096 + bw0] = (u8)(int)rintf(h * 127.0f); \
    h16 = f2b(h); \
  } \
  EXTRA \
  BARX(); \
} while (0)

__global__ __launch_bounds__(512, 1)
void k_scan15(const int* wq_, const int* __restrict__ xqd,
              const float* __restrict__ sb, u16* __restrict__ hs) {
  __shared__ u8 bimg[2 * 4096];        // swizzled i8 h image (rows 2..15 stay 0)
  __shared__ int gimg[8 * GS2];        // raw AH rows: [(l15*4+g)*GS2 + col]
  __shared__ floatx4 xg[2][16 * XS];   // wave-local dbuf, prescaled (x log2e)
  const int tid = threadIdx.x;
  const int w = tid >> 6, lane = tid & 63;
  const int l15 = lane & 15, kq = lane >> 4;
  const int bg = blockIdx.x;

  *(uint4*)&bimg[tid * 16] = (uint4){0, 0, 0, 0};

  intx4 wfr[40];
  {
    const intx4* wp = (const intx4*)wq_ + (size_t)(w * 40) * 64 + lane;
#pragma unroll
    for (int F = 0; F < 40; ++F) wfr[F] = wp[(size_t)F * 64];
  }
  const float L2E = 1.44269504f;
  const float A_h = sb[0], A_x = sb[1];
  const float Ah1 = A_h * L2E, Ah2 = A_h * 2.0f * L2E;
  const float Sx1 = A_x * L2E, Sx2 = A_x * 2.0f * L2E;
  const float T2L2E = 2.0f * L2E;

  const int* xu = xqd + (size_t)bg * 65536;    // 256 units x 256 dwords
  const int wcol = w * 32 + kq * 4;            // producer cols: + ht*16 + rr
  const int lr = lane >> 5, lc = lane & 31;
  const int mycol = w * 32 + lc;               // this lane's cell (row lr)
  const int bw0 = lr * 256 + (((mycol >> 4) ^ lr) << 4) + (mycol & 15);
  // precomputed addresses
  const int bA0 = l15 * 256 + ((((0 * 4 + kq) ^ l15) & 15) << 4);
  const int bA1 = l15 * 256 + ((((1 * 4 + kq) ^ l15) & 15) << 4);
  const int bA2 = l15 * 256 + ((((2 * 4 + kq) ^ l15) & 15) << 4);
  const int bA3 = l15 * 256 + ((((3 * 4 + kq) ^ l15) & 15) << 4);
  int* gw = &gimg[(l15 * 4) * GS2 + w * 32 + kq * 4];   // store base (+g*GS2+ht*16)
  const int* gr = &gimg[(lr * 4) * GS2 + mycol];        // read base (+g*GS2)
  u16* hgp = hs + ((size_t)(bg * 2 + lr) * TT) * 256 + mycol;

  // prologue: xg[0] from chunk-0 frags; xn = chunk-1 frags
  {
    intx4 xcm = *(const intx4*)(xu + lane * 4);
    intx4 xcr = *(const intx4*)(xu + 256 + lane * 4);
    phaseg<0>(wfr, xcm, xcr, xg[0], l15, wcol, Sx1, Sx2, Ah1, Ah2);
    phaseg<1>(wfr, xcm, xcr, xg[0], l15, wcol, Sx1, Sx2, Ah1, Ah2);
  }
  intx4 xnm = *(const intx4*)(xu + 512 + lane * 4);
  intx4 xnr = *(const intx4*)(xu + 512 + 256 + lane * 4);

  float c_st = 0.f;
  u16 h16 = 0;
  __syncthreads();   // bimg zero + xg[0] visible

  for (int ch = 0; ch < 128; ++ch) {
    const int rb = ch & 1;
    const floatx4* xgr = xg[rb];
    floatx4* xgw2 = xg[rb ^ 1];
    u16* hb = hgp + (size_t)ch * 2048;
    STEP(0, phaseg<0>(wfr, xnm, xnr, xgw2, l15, wcol, Sx1, Sx2, Ah1, Ah2););
    STEP(1, phaseg<1>(wfr, xnm, xnr, xgw2, l15, wcol, Sx1, Sx2, Ah1, Ah2););
    STEP(2, { const int chn = ch + 2 < 128 ? ch + 2 : 127;
              xnm = *(const intx4*)(xu + chn * 512 + lane * 4);
              xnr = *(const intx4*)(xu + chn * 512 + 256 + lane * 4); });
    STEP(3, ;);
    STEP(4, ;);
    STEP(5, ;);
    STEP(6, ;);
    STEP(7, ;);
  }
  hgp[(size_t)(TT - 1) * 256] = h16;
}

// ---------------- post heads (unchanged, proven) ----------------

__global__ __launch_bounds__(256, 2)
void k_act(const u16* __restrict__ hs, const u16* __restrict__ wafc1,
           const u16* __restrict__ waout, const float* __restrict__ b_afc1,
           const float* __restrict__ b_aout, float* __restrict__ act) {
  __shared__ u16 a_sh[16 * 264];
  __shared__ u16 z_sh[16 * 264];
  __shared__ float sb1[256];
  const int tid = threadIdx.x;
  const int wave = tid >> 6, lane = tid & 63;
  const int l15 = lane & 15, kq = lane >> 4;
  const size_t bt0 = (size_t)blockIdx.x * 16;
  sb1[tid] = b_afc1[tid];
#pragma unroll
  for (int i = 0; i < 2; ++i) {
    int chunk = i * 256 + tid;
    int row = chunk >> 5, c = chunk & 31;
    *(uint4*)&a_sh[row * 264 + c * 8] = *(const uint4*)(hs + (bt0 + row) * 256 + c * 8);
  }
  __syncthreads();
  floatx4 acc[4];
#pragma unroll
  for (int nt = 0; nt < 4; ++nt) acc[nt] = (floatx4){0.f, 0.f, 0.f, 0.f};
#pragma unroll
  for (int kt = 0; kt < 8; ++kt) {
    short8 a = *(const short8*)&a_sh[l15 * 264 + kt * 32 + kq * 8];
#pragma unroll
    for (int nt = 0; nt < 4; ++nt) {
      int n = wave * 64 + nt * 16 + l15;
      short8 b = *(const short8*)(wafc1 + n * 256 + kt * 32 + kq * 8);
      acc[nt] = __builtin_amdgcn_mfma_f32_16x16x32_bf16(a, b, acc[nt], 0, 0, 0);
    }
  }
#pragma unroll
  for (int nt = 0; nt < 4; ++nt) {
    int n = wave * 64 + nt * 16 + l15;
    float bb = sb1[n];
#pragma unroll
    for (int r = 0; r < 4; ++r) {
      float v = acc[nt][r] + bb;
      v = v > 0.f ? v : 0.f;
      z_sh[(kq * 4 + r) * 264 + n] = f2b(v);
    }
  }
  __syncthreads();
  if (wave == 0) {
    floatx4 a2 = (floatx4){0.f, 0.f, 0.f, 0.f};
#pragma unroll
    for (int kt = 0; kt < 8; ++kt) {
      short8 a = *(const short8*)&z_sh[l15 * 264 + kt * 32 + kq * 8];
      short8 b = *(const short8*)(waout + l15 * 256 + kt * 32 + kq * 8);
      a2 = __builtin_amdgcn_mfma_f32_16x16x32_bf16(a, b, a2, 0, 0, 0);
    }
    if (l15 < 8) {
      float bb = b_aout[l15];
#pragma unroll
      for (int r = 0; r < 4; ++r)
        act[(bt0 + (size_t)(kq * 4 + r)) * 8 + l15] = a2[r] + bb;
    }
  }
}

__global__ __launch_bounds__(256, 2)
void k_cb(const u16* __restrict__ hs, const float* __restrict__ x,
          const u16* __restrict__ wcb, const float* __restrict__ b_cont,
          const float* __restrict__ b_bin, float* __restrict__ dout) {
  __shared__ u16 a_sh[16 * 296];
  const int tid = threadIdx.x;
  const int wave = tid >> 6, lane = tid & 63;
  const int l15 = lane & 15, kq = lane >> 4;
  const size_t bt0 = (size_t)blockIdx.x * 16;
#pragma unroll
  for (int i = 0; i < 2; ++i) {
    int chunk = i * 256 + tid;
    int row = chunk >> 5, c = chunk & 31;
    *(uint4*)&a_sh[row * 296 + c * 8] = *(const uint4*)(hs + (bt0 + row) * 256 + c * 8);
  }
  if (tid < 128) {
    int m = tid >> 3, j = tid & 7;
    a_sh[m * 296 + 256 + j] = f2b(x[(bt0 + m) * 43 + 35 + j]);
  }
  for (int i = tid; i < 384; i += 256) {
    int m = i / 24, jj = i % 24;
    a_sh[m * 296 + 264 + jj] = 0;
  }
  __syncthreads();
  const int n = wave * 16 + l15;
  floatx4 acc = (floatx4){0.f, 0.f, 0.f, 0.f};
#pragma unroll
  for (int kt = 0; kt < 9; ++kt) {
    short8 a = *(const short8*)&a_sh[l15 * 296 + kt * 32 + kq * 8];
    short8 b = *(const short8*)(wcb + n * 288 + kt * 32 + kq * 8);
    acc = __builtin_amdgcn_mfma_f32_16x16x32_bf16(a, b, acc, 0, 0, 0);
  }
  if (n < 50) {
    float bb = b_cont[n];
#pragma unroll
    for (int r = 0; r < 4; ++r)
      dout[(bt0 + (size_t)(kq * 4 + r)) * 50 + n] = acc[r] + bb;
  } else if (n < 60) {
    float bb = b_bin[n - 50];
#pragma unroll
    for (int r = 0; r < 4; ++r)
      dout[BIN_OFF + (bt0 + (size_t)(kq * 4 + r)) * 10 + (n - 50)] = sigmf(acc[r] + bb);
  }
}

// ---------------- launch ----------------
extern "C" void kernel_launch(void* const* d_in, const int* in_sizes, int n_in,
                              void* d_out, int out_size, void* d_ws, size_t ws_size,
                              hipStream_t stream) {
  const float* x      = (const float*)d_in[0];
  const float* W_ih   = (const float*)d_in[1];
  const float* W_hh   = (const float*)d_in[2];
  const float* b_ih   = (const float*)d_in[3];
  const float* b_hh   = (const float*)d_in[4];
  const float* W_afc1 = (const float*)d_in[5];
  const float* b_afc1 = (const float*)d_in[6];
  const float* W_aout = (const float*)d_in[7];
  const float* b_aout = (const float*)d_in[8];
  const float* W_cont = (const float*)d_in[9];
  const float* b_cont = (const float*)d_in[10];
  const float* W_bin  = (const float*)d_in[11];
  const float* b_bin  = (const float*)d_in[12];
  float* outf = (float*)d_out;
  char* ws = (char*)d_ws;

  u32*   am     = (u32*)(ws);                    //         64 B
  float* bias   = (float*)(ws + 64);             //      4,096 B
  float* sbuf   = (float*)(ws + 4160);           //         64 B
  int*   wq     = (int*)(ws + 4224);             //    327,680 B
  u16*   wafc1b = (u16*)(ws + 331904);           //    131,072 B
  u16*   waoutb = (u16*)(ws + 462976);           //      8,192 B
  u16*   wcbb   = (u16*)(ws + 471168);           //     36,864 B
  int*   xqd    = (int*)(ws + 524288);           // 16,777,216 B (+4K pad)
  u16*   hs     = (u16*)(ws + 17305600);         // 67,108,864 B (end 84,414,464)

  hipLaunchKernelGGL(k_zero4, dim3(1), dim3(64), 0, stream, am);
  hipLaunchKernelGGL(k_amax, dim3(2048), dim3(256), 0, stream, x, W_ih, W_hh, am);
  hipLaunchKernelGGL(k_prep_bias, dim3(4), dim3(256), 0, stream, b_ih, b_hh, bias);
  hipLaunchKernelGGL(k_prep_wq2, dim3(320), dim3(256), 0, stream, W_ih, W_hh, bias, am, wq, sbuf);
  hipLaunchKernelGGL(k_prep_xq2, dim3(16384), dim3(256), 0, stream, x, am, xqd);
  hipLaunchKernelGGL(k_prep_afc, dim3(272), dim3(256), 0, stream, W_afc1, W_aout, wafc1b, waoutb);
  hipLaunchKernelGGL(k_prep_wcb, dim3(64), dim3(288), 0, stream, W_cont, W_bin, wcbb);
  hipLaunchKernelGGL(k_scan15, dim3(64), dim3(512), 0, stream, wq, xqd, sbuf, hs);
  hipLaunchKernelGGL(k_act, dim3(8192), dim3(256), 0, stream, hs, wafc1b, waoutb, b_afc1, b_aout, outf + ACT_OFF);
  hipLaunchKernelGGL(k_cb, dim3(8192), dim3(256), 0, stream, hs, x, wcbb, b_cont, b_bin, outf);
}

// Round 9
// 1314.643 us; speedup vs baseline: 1.0197x; 1.0197x over previous
//
#include <hip/hip_runtime.h>

typedef unsigned int u32;
typedef unsigned short u16;
typedef unsigned char u8;
typedef unsigned long long u64;
typedef __attribute__((ext_vector_type(8))) short short8;
typedef __attribute__((ext_vector_type(4))) float floatx4;
typedef __attribute__((ext_vector_type(4))) int intx4;

#define TT 1024
#define BIN_OFF 6553600
#define ACT_OFF 7864320

__device__ __forceinline__ u16 f2b(float f) {
  u32 u = __builtin_bit_cast(u32, f);
  u += 0x7fffu + ((u >> 16) & 1u);
  return (u16)(u >> 16);
}
__device__ __forceinline__ float sigmf(float x) { return 1.0f / (1.0f + __expf(-x)); }
// raw 2^x: single v_exp_f32 (OCML exp2f adds safe-path overhead we don't need;
// inputs are clamped). s_nop 1 covers the trans->consumer wait state the
// compiler won't insert around inline asm.
__device__ __forceinline__ float exp2i(float x) {
  float r;
  asm volatile("v_exp_f32 %0, %1\n\ts_nop 1" : "=v"(r) : "v"(x));
  return r;
}

// ---------------- prep ----------------

__global__ void k_zero4(u32* __restrict__ p) {
  if (threadIdx.x < 4) p[threadIdx.x] = 0;
}
// absmax of x / W_hh / W_ih -> am[0..2].  grid 2048 x 256
__global__ void k_amax(const float* __restrict__ x, const float* __restrict__ wih,
                       const float* __restrict__ whh, u32* __restrict__ am) {
  __shared__ float red[256];
  const int tid = threadIdx.x;
  int b = blockIdx.x;
  const float* src; size_t n; int sec, b0, nb;
  if (b < 1920)      { src = x;   n = 5636096; sec = 0; b0 = 0;    nb = 1920; }
  else if (b < 2016) { src = whh; n = 262144;  sec = 1; b0 = 1920; nb = 96; }
  else               { src = wih; n = 44032;   sec = 2; b0 = 2016; nb = 32; }
  float m = 0.f;
  for (size_t i = (size_t)(b - b0) * 256 + tid; i < n; i += (size_t)nb * 256)
    m = fmaxf(m, fabsf(src[i]));
  red[tid] = m;
  __syncthreads();
  for (int s = 128; s > 0; s >>= 1) {
    if (tid < s) red[tid] = fmaxf(red[tid], red[tid + s]);
    __syncthreads();
  }
  if (tid == 0) atomicMax(&am[sec], __float_as_uint(red[0]));
}
// bias = b_ih + b_hh.  grid 4 x 256
__global__ void k_prep_bias(const float* __restrict__ a, const float* __restrict__ b,
                            float* __restrict__ o) {
  int i = blockIdx.x * 256 + threadIdx.x;
  o[i] = a[i] + b[i];
}
// i8 weight frags. Per wave w: 40 frags, F = tile*5 + c (tile = gate*2+ht;
// c 0..3 h-chunks scale sn_h, c=4 x-chunk scale sn_x, with bias codes at
// k=43 (coarse, unit 127*A_x) and k=44 (fine, unit 127*A_h)).
// A-frag lane l: n = gate*256+w*32+ht*16+(l&15); k = (l>>4)*16 + jq*4 + b.
// grid 320 x 256
__global__ void k_prep_wq2(const float* __restrict__ wih, const float* __restrict__ whh,
                           const float* __restrict__ bias, const u32* __restrict__ am,
                           int* __restrict__ wq, float* __restrict__ sbuf) {
  u32 idx = blockIdx.x * 256 + threadIdx.x;
  const float xmax = fmaxf(__uint_as_float(am[0]), 1e-8f);
  const float whm  = fmaxf(__uint_as_float(am[1]), 1e-8f);
  const float wxm  = fmaxf(__uint_as_float(am[2]), 1e-8f);
  const float sn_h = whm / 127.0f, sn_x = wxm / 127.0f;
  const float sx = xmax / 127.0f;
  const float A_h = sn_h / 127.0f;          // unit of wh_int*h_int and of x-res path
  const float A_x = sn_x * sx;              // unit of wx_int*x_int
  if (idx == 0) { sbuf[0] = A_h; sbuf[1] = A_x; }
  int jq = idx & 3;
  int lane = (idx >> 2) & 63;
  u32 wf = idx >> 8;                        // w*40 + F, < 320
  int F = wf % 40, w = wf / 40;
  int tile = F / 5, c = F % 5;
  int gate = tile >> 1, ht = tile & 1;
  int l15 = lane & 15, kq = lane >> 4;
  int n = gate * 256 + w * 32 + ht * 16 + l15;
  u32 out = 0;
#pragma unroll
  for (int b = 0; b < 4; ++b) {
    int kl = kq * 16 + jq * 4 + b;
    float q = 0.f;
    if (c < 4) {
      q = rintf(whh[n * 256 + c * 64 + kl] / sn_h);
    } else {
      if (kl < 43) q = rintf(wih[n * 43 + kl] / sn_x);
      else if (kl == 43) {
        q = fminf(fmaxf(rintf(bias[n] / (127.0f * A_x)), -127.f), 127.f);
      } else if (kl == 44) {
        float qc = fminf(fmaxf(rintf(bias[n] / (127.0f * A_x)), -127.f), 127.f);
        q = rintf((bias[n] - qc * 127.0f * A_x) / (127.0f * A_h));
      }
    }
    q = fminf(fmaxf(q, -127.f), 127.f);
    int qi = (int)q;
    out |= ((u32)(qi & 255)) << (8 * b);
  }
  wq[idx] = (int)out;
}
// chunk-packed i8 x-image B-frags (full 16-slot M!):
// per (bg, mt, res) one 1KB unit, unit index = bg*256 + mt*2 + res.
// unit byte[m*64 + k]: m = tloc*2 + r (t = mt*8 + tloc, row = bg*2 + r).
// k<35: x[row][t][k]; 35..42: x[row][t-1][k]; 43: main 127 / res 0 (bias
// coarse slot); 44: main 0 / res 127 (bias fine slot); 45..63: 0.
// main scale sx, residual scale sr = A_h/sn_x.
// grid 16384 x 256
__global__ void k_prep_xq2(const float* __restrict__ x, const u32* __restrict__ am,
                           int* __restrict__ xq) {
  u32 idx = blockIdx.x * 256 + threadIdx.x;
  const float xmax = fmaxf(__uint_as_float(am[0]), 1e-8f);
  const float whm  = fmaxf(__uint_as_float(am[1]), 1e-8f);
  const float wxm  = fmaxf(__uint_as_float(am[2]), 1e-8f);
  const float sx = xmax / 127.0f;
  const float sr = whm / (127.0f * wxm);    // A_h / sn_x
  u32 unit = idx >> 8;                      // bg*256 + mt*2 + res
  u32 dwIn = idx & 255;
  int lane = dwIn >> 2, reg = dwIn & 3;
  int m = lane & 15, kq = lane >> 4;
  int bg = unit >> 8;
  int rem = unit & 255;
  int mt = rem >> 1, res = rem & 1;
  int t = mt * 8 + (m >> 1);
  int row = bg * 2 + (m & 1);
  u32 out = 0;
#pragma unroll
  for (int b = 0; b < 4; ++b) {
    int k = kq * 16 + reg * 4 + b;
    int q = 0;
    if (k < 43) {
      float xv = 0.f;
      if (k < 35) xv = x[((size_t)row * TT + t) * 43 + k];
      else if (t > 0) xv = x[((size_t)row * TT + (t - 1)) * 43 + k];
      float q1 = fminf(fmaxf(rintf(xv / sx), -127.f), 127.f);
      if (!res) q = (int)q1;
      else q = (int)fminf(fmaxf(rintf((xv - sx * q1) / sr), -127.f), 127.f);
    } else if (k == 43) q = res ? 0 : 127;
    else if (k == 44) q = res ? 127 : 0;
    out |= ((u32)(q & 255)) << (8 * b);
  }
  xq[idx] = (int)out;
}
// W_afc1 (256x256) and W_aout padded to 16x256.  grid 272 x 256
__global__ void k_prep_afc(const float* __restrict__ wafc1, const float* __restrict__ waout,
                           u16* __restrict__ ob1, u16* __restrict__ ob2) {
  int r = blockIdx.x, k = threadIdx.x;
  if (r < 256) ob1[r * 256 + k] = f2b(wafc1[r * 256 + k]);
  else {
    int y = r - 256;
    ob2[y * 256 + k] = f2b(y < 8 ? waout[y * 256 + k] : 0.f);
  }
}
// Wcb[64][288].  grid 64 x 288
__global__ void k_prep_wcb(const float* __restrict__ wcont, const float* __restrict__ wbin,
                           u16* __restrict__ o) {
  int nrow = blockIdx.x, k = threadIdx.x;
  float v = 0.f;
  if (k < 264) {
    if (nrow < 50) v = wcont[nrow * 264 + k];
    else if (nrow < 60) v = wbin[(nrow - 50) * 264 + k];
  }
  o[nrow * 288 + k] = f2b(v);
}

// ---------------- LSTM scan v16: v15 + raw v_exp_f32 ----------------
// v15 post-mortem: conflict fix matched (1.678e7 -> 0) but time neutral ->
// LDS serialization was hidden under the MFMA phase. Step = 2506 cyc:
// MFMA 1100 (= saturated issue floor for 68 MFMA/SIMD at ~16 cyc), VALU 970,
// sync/latency ~430. Overlap blocked by the phase-locked barrier (fully
// coupled recurrence). v16 attacks the VALU phase: the 5 exp2f() calls
// lower to OCML __ocml_exp2_f32 (safe-path, ~5-8 inst each) because no
// fast-math; replace with 1-inst inline-asm v_exp_f32 (+s_nop hazard guard).
// Everything else byte-identical to v15 (GS2=268 conflict-free stride kept).
#define XS 257
#define GS2 268
#define BARX() do { \
  asm volatile("s_waitcnt lgkmcnt(0)" ::: "memory"); \
  __builtin_amdgcn_s_barrier(); \
  __builtin_amdgcn_sched_barrier(0); \
} while (0)

// phase-G half: x-main + x-res MFMAs for 4 gates of half HT, prescaled combine
template <int HT>
__device__ __forceinline__ void phaseg(const intx4 (&wfr)[40], intx4 xm, intx4 xr,
                                       floatx4* xgw, int l15, int wcol,
                                       float Sx1, float Sx2, float Ah1, float Ah2) {
  const intx4 z = {0, 0, 0, 0};
  intx4 AX[4], AR[4];
#pragma unroll
  for (int g = 0; g < 4; ++g) {
    const int F = (g * 2 + HT) * 5 + 4;
    AX[g] = __builtin_amdgcn_mfma_i32_16x16x64_i8(wfr[F], xm, z, 0, 0, 0);
    AR[g] = __builtin_amdgcn_mfma_i32_16x16x64_i8(wfr[F], xr, z, 0, 0, 0);
  }
#pragma unroll
  for (int rr = 0; rr < 4; ++rr) {
    floatx4 P;
#pragma unroll
    for (int g = 0; g < 4; ++g) {
      const float sx = (g == 2) ? Sx2 : Sx1;
      const float sh = (g == 2) ? Ah2 : Ah1;
      P[g] = fmaf(sx, (float)AX[g][rr], sh * (float)AR[g][rr]);
    }
    xgw[l15 * XS + wcol + HT * 16 + rr] = P;
  }
}

#define MCH(DST, G, HT) { \
  const int F_ = ((G) * 2 + (HT)) * 5; \
  intx4 a_ = __builtin_amdgcn_mfma_i32_16x16x64_i8(wfr[F_ + 0], bh0, z, 0, 0, 0); \
  a_ = __builtin_amdgcn_mfma_i32_16x16x64_i8(wfr[F_ + 1], bh1, a_, 0, 0, 0); \
  a_ = __builtin_amdgcn_mfma_i32_16x16x64_i8(wfr[F_ + 2], bh2, a_, 0, 0, 0); \
  DST = __builtin_amdgcn_mfma_i32_16x16x64_i8(wfr[F_ + 3], bh3, a_, 0, 0, 0); \
}

#define STEP(TL, EXTRA) do { \
  enum { CUR = (TL) & 1, NXT = CUR ^ 1 }; \
  if ((TL) == 0) { if (ch > 0) hb[-256] = h16; } \
  else hb[((TL) - 1) * 256] = h16; \
  intx4 bh0 = *(const intx4*)&bimg[CUR * 4096 + bA0]; \
  intx4 bh1 = *(const intx4*)&bimg[CUR * 4096 + bA1]; \
  intx4 bh2 = *(const intx4*)&bimg[CUR * 4096 + bA2]; \
  intx4 bh3 = *(const intx4*)&bimg[CUR * 4096 + bA3]; \
  floatx4 P = xgr[((TL) * 2 + lr) * XS + mycol]; \
  const intx4 z = {0, 0, 0, 0}; \
  intx4 A0, A1, A2, A3, A4, A5, A6, A7; \
  __builtin_amdgcn_s_setprio(1); \
  MCH(A0, 0, 0) MCH(A1, 1, 0) MCH(A2, 2, 0) MCH(A3, 3, 0) \
  MCH(A4, 0, 1) MCH(A5, 1, 1) MCH(A6, 2, 1) MCH(A7, 3, 1) \
  __builtin_amdgcn_s_setprio(0); \
  if (l15 < 2) { \
    *(intx4*)&gw[0 * GS2 +  0] = A0; *(intx4*)&gw[1 * GS2 +  0] = A1; \
    *(intx4*)&gw[2 * GS2 +  0] = A2; *(intx4*)&gw[3 * GS2 +  0] = A3; \
    *(intx4*)&gw[0 * GS2 + 16] = A4; *(intx4*)&gw[1 * GS2 + 16] = A5; \
    *(intx4*)&gw[2 * GS2 + 16] = A6; *(intx4*)&gw[3 * GS2 + 16] = A7; \
  } \
  asm volatile("s_waitcnt lgkmcnt(0)" ::: "memory"); \
  __builtin_amdgcn_sched_barrier(0); \
  { \
    float a0 = (float)gr[0 * GS2], a1 = (float)gr[1 * GS2]; \
    float a2 = (float)gr[2 * GS2], a3 = (float)gr[3 * GS2]; \
    float zz0 = fmaf(Ah1, a0, P[0]); \
    float zz1 = fmaf(Ah1, a1, P[1]); \
    float zz2 = fminf(fmaf(Ah2, a2, P[2]), 43.0f); \
    float zz3 = fmaf(Ah1, a3, P[3]); \
    float iv = __builtin_amdgcn_rcpf(1.0f + exp2i(-zz0)); \
    float fv = __builtin_amdgcn_rcpf(1.0f + exp2i(-zz1)); \
    float eg = exp2i(zz2); \
    float gv = (eg - 1.0f) * __builtin_amdgcn_rcpf(eg + 1.0f); \
    float ov = __builtin_amdgcn_rcpf(1.0f + exp2i(-zz3)); \
    float cc = fv * c_st + iv * gv; \
    c_st = cc; \
    float dd = fminf(cc * T2L2E, 43.0f); \
    float ec = exp2i(dd); \
    float th = (ec - 1.0f) * __builtin_amdgcn_rcpf(ec + 1.0f); \
    float h = ov * th; \
    bimg[NXT * 4096 + bw0] = (u8)(int)rintf(h * 127.0f); \
    h16 = f2b(h); \
  } \
  EXTRA \
  BARX(); \
} while (0)

__global__ __launch_bounds__(512, 1)
void k_scan16(const int* wq_, const int* __restrict__ xqd,
              const float* __restrict__ sb, u16* __restrict__ hs) {
  __shared__ u8 bimg[2 * 4096];        // swizzled i8 h image (rows 2..15 stay 0)
  __shared__ int gimg[8 * GS2];        // raw AH rows: [(l15*4+g)*GS2 + col]
  __shared__ floatx4 xg[2][16 * XS];   // wave-local dbuf, prescaled (x log2e)
  const int tid = threadIdx.x;
  const int w = tid >> 6, lane = tid & 63;
  const int l15 = lane & 15, kq = lane >> 4;
  const int bg = blockIdx.x;

  *(uint4*)&bimg[tid * 16] = (uint4){0, 0, 0, 0};

  intx4 wfr[40];
  {
    const intx4* wp = (const intx4*)wq_ + (size_t)(w * 40) * 64 + lane;
#pragma unroll
    for (int F = 0; F < 40; ++F) wfr[F] = wp[(size_t)F * 64];
  }
  const float L2E = 1.44269504f;
  const float A_h = sb[0], A_x = sb[1];
  const float Ah1 = A_h * L2E, Ah2 = A_h * 2.0f * L2E;
  const float Sx1 = A_x * L2E, Sx2 = A_x * 2.0f * L2E;
  const float T2L2E = 2.0f * L2E;

  const int* xu = xqd + (size_t)bg * 65536;    // 256 units x 256 dwords
  const int wcol = w * 32 + kq * 4;            // producer cols: + ht*16 + rr
  const int lr = lane >> 5, lc = lane & 31;
  const int mycol = w * 32 + lc;               // this lane's cell (row lr)
  const int bw0 = lr * 256 + (((mycol >> 4) ^ lr) << 4) + (mycol & 15);
  // precomputed addresses
  const int bA0 = l15 * 256 + ((((0 * 4 + kq) ^ l15) & 15) << 4);
  const int bA1 = l15 * 256 + ((((1 * 4 + kq) ^ l15) & 15) << 4);
  const int bA2 = l15 * 256 + ((((2 * 4 + kq) ^ l15) & 15) << 4);
  const int bA3 = l15 * 256 + ((((3 * 4 + kq) ^ l15) & 15) << 4);
  int* gw = &gimg[(l15 * 4) * GS2 + w * 32 + kq * 4];   // store base (+g*GS2+ht*16)
  const int* gr = &gimg[(lr * 4) * GS2 + mycol];        // read base (+g*GS2)
  u16* hgp = hs + ((size_t)(bg * 2 + lr) * TT) * 256 + mycol;

  // prologue: xg[0] from chunk-0 frags; xn = chunk-1 frags
  {
    intx4 xcm = *(const intx4*)(xu + lane * 4);
    intx4 xcr = *(const intx4*)(xu + 256 + lane * 4);
    phaseg<0>(wfr, xcm, xcr, xg[0], l15, wcol, Sx1, Sx2, Ah1, Ah2);
    phaseg<1>(wfr, xcm, xcr, xg[0], l15, wcol, Sx1, Sx2, Ah1, Ah2);
  }
  intx4 xnm = *(const intx4*)(xu + 512 + lane * 4);
  intx4 xnr = *(const intx4*)(xu + 512 + 256 + lane * 4);

  float c_st = 0.f;
  u16 h16 = 0;
  __syncthreads();   // bimg zero + xg[0] visible

  for (int ch = 0; ch < 128; ++ch) {
    const int rb = ch & 1;
    const floatx4* xgr = xg[rb];
    floatx4* xgw2 = xg[rb ^ 1];
    u16* hb = hgp + (size_t)ch * 2048;
    STEP(0, phaseg<0>(wfr, xnm, xnr, xgw2, l15, wcol, Sx1, Sx2, Ah1, Ah2););
    STEP(1, phaseg<1>(wfr, xnm, xnr, xgw2, l15, wcol, Sx1, Sx2, Ah1, Ah2););
    STEP(2, { const int chn = ch + 2 < 128 ? ch + 2 : 127;
              xnm = *(const intx4*)(xu + chn * 512 + lane * 4);
              xnr = *(const intx4*)(xu + chn * 512 + 256 + lane * 4); });
    STEP(3, ;);
    STEP(4, ;);
    STEP(5, ;);
    STEP(6, ;);
    STEP(7, ;);
  }
  hgp[(size_t)(TT - 1) * 256] = h16;
}

// ---------------- post heads (unchanged, proven) ----------------

__global__ __launch_bounds__(256, 2)
void k_act(const u16* __restrict__ hs, const u16* __restrict__ wafc1,
           const u16* __restrict__ waout, const float* __restrict__ b_afc1,
           const float* __restrict__ b_aout, float* __restrict__ act) {
  __shared__ u16 a_sh[16 * 264];
  __shared__ u16 z_sh[16 * 264];
  __shared__ float sb1[256];
  const int tid = threadIdx.x;
  const int wave = tid >> 6, lane = tid & 63;
  const int l15 = lane & 15, kq = lane >> 4;
  const size_t bt0 = (size_t)blockIdx.x * 16;
  sb1[tid] = b_afc1[tid];
#pragma unroll
  for (int i = 0; i < 2; ++i) {
    int chunk = i * 256 + tid;
    int row = chunk >> 5, c = chunk & 31;
    *(uint4*)&a_sh[row * 264 + c * 8] = *(const uint4*)(hs + (bt0 + row) * 256 + c * 8);
  }
  __syncthreads();
  floatx4 acc[4];
#pragma unroll
  for (int nt = 0; nt < 4; ++nt) acc[nt] = (floatx4){0.f, 0.f, 0.f, 0.f};
#pragma unroll
  for (int kt = 0; kt < 8; ++kt) {
    short8 a = *(const short8*)&a_sh[l15 * 264 + kt * 32 + kq * 8];
#pragma unroll
    for (int nt = 0; nt < 4; ++nt) {
      int n = wave * 64 + nt * 16 + l15;
      short8 b = *(const short8*)(wafc1 + n * 256 + kt * 32 + kq * 8);
      acc[nt] = __builtin_amdgcn_mfma_f32_16x16x32_bf16(a, b, acc[nt], 0, 0, 0);
    }
  }
#pragma unroll
  for (int nt = 0; nt < 4; ++nt) {
    int n = wave * 64 + nt * 16 + l15;
    float bb = sb1[n];
#pragma unroll
    for (int r = 0; r < 4; ++r) {
      float v = acc[nt][r] + bb;
      v = v > 0.f ? v : 0.f;
      z_sh[(kq * 4 + r) * 264 + n] = f2b(v);
    }
  }
  __syncthreads();
  if (wave == 0) {
    floatx4 a2 = (floatx4){0.f, 0.f, 0.f, 0.f};
#pragma unroll
    for (int kt = 0; kt < 8; ++kt) {
      short8 a = *(const short8*)&z_sh[l15 * 264 + kt * 32 + kq * 8];
      short8 b = *(const short8*)(waout + l15 * 256 + kt * 32 + kq * 8);
      a2 = __builtin_amdgcn_mfma_f32_16x16x32_bf16(a, b, a2, 0, 0, 0);
    }
    if (l15 < 8) {
      float bb = b_aout[l15];
#pragma unroll
      for (int r = 0; r < 4; ++r)
        act[(bt0 + (size_t)(kq * 4 + r)) * 8 + l15] = a2[r] + bb;
    }
  }
}

__global__ __launch_bounds__(256, 2)
void k_cb(const u16* __restrict__ hs, const float* __restrict__ x,
          const u16* __restrict__ wcb, const float* __restrict__ b_cont,
          const float* __restrict__ b_bin, float* __restrict__ dout) {
  __shared__ u16 a_sh[16 * 296];
  const int tid = threadIdx.x;
  const int wave = tid >> 6, lane = tid & 63;
  const int l15 = lane & 15, kq = lane >> 4;
  const size_t bt0 = (size_t)blockIdx.x * 16;
#pragma unroll
  for (int i = 0; i < 2; ++i) {
    int chunk = i * 256 + tid;
    int row = chunk >> 5, c = chunk & 31;
    *(uint4*)&a_sh[row * 296 + c * 8] = *(const uint4*)(hs + (bt0 + row) * 256 + c * 8);
  }
  if (tid < 128) {
    int m = tid >> 3, j = tid & 7;
    a_sh[m * 296 + 256 + j] = f2b(x[(bt0 + m) * 43 + 35 + j]);
  }
  for (int i = tid; i < 384; i += 256) {
    int m = i / 24, jj = i % 24;
    a_sh[m * 296 + 264 + jj] = 0;
  }
  __syncthreads();
  const int n = wave * 16 + l15;
  floatx4 acc = (floatx4){0.f, 0.f, 0.f, 0.f};
#pragma unroll
  for (int kt = 0; kt < 9; ++kt) {
    short8 a = *(const short8*)&a_sh[l15 * 296 + kt * 32 + kq * 8];
    short8 b = *(const short8*)(wcb + n * 288 + kt * 32 + kq * 8);
    acc = __builtin_amdgcn_mfma_f32_16x16x32_bf16(a, b, acc, 0, 0, 0);
  }
  if (n < 50) {
    float bb = b_cont[n];
#pragma unroll
    for (int r = 0; r < 4; ++r)
      dout[(bt0 + (size_t)(kq * 4 + r)) * 50 + n] = acc[r] + bb;
  } else if (n < 60) {
    float bb = b_bin[n - 50];
#pragma unroll
    for (int r = 0; r < 4; ++r)
      dout[BIN_OFF + (bt0 + (size_t)(kq * 4 + r)) * 10 + (n - 50)] = sigmf(acc[r] + bb);
  }
}

// ---------------- launch ----------------
extern "C" void kernel_launch(void* const* d_in, const int* in_sizes, int n_in,
                              void* d_out, int out_size, void* d_ws, size_t ws_size,
                              hipStream_t stream) {
  const float* x      = (const float*)d_in[0];
  const float* W_ih   = (const float*)d_in[1];
  const float* W_hh   = (const float*)d_in[2];
  const float* b_ih   = (const float*)d_in[3];
  const float* b_hh   = (const float*)d_in[4];
  const float* W_afc1 = (const float*)d_in[5];
  const float* b_afc1 = (const float*)d_in[6];
  const float* W_aout = (const float*)d_in[7];
  const float* b_aout = (const float*)d_in[8];
  const float* W_cont = (const float*)d_in[9];
  const float* b_cont = (const float*)d_in[10];
  const float* W_bin  = (const float*)d_in[11];
  const float* b_bin  = (const float*)d_in[12];
  float* outf = (float*)d_out;
  char* ws = (char*)d_ws;

  u32*   am     = (u32*)(ws);                    //         64 B
  float* bias   = (float*)(ws + 64);             //      4,096 B
  float* sbuf   = (float*)(ws + 4160);           //         64 B
  int*   wq     = (int*)(ws + 4224);             //    327,680 B
  u16*   wafc1b = (u16*)(ws + 331904);           //    131,072 B
  u16*   waoutb = (u16*)(ws + 462976);           //      8,192 B
  u16*   wcbb   = (u16*)(ws + 471168);           //     36,864 B
  int*   xqd    = (int*)(ws + 524288);           // 16,777,216 B (+4K pad)
  u16*   hs     = (u16*)(ws + 17305600);         // 67,108,864 B (end 84,414,464)

  hipLaunchKernelGGL(k_zero4, dim3(1), dim3(64), 0, stream, am);
  hipLaunchKernelGGL(k_amax, dim3(2048), dim3(256), 0, stream, x, W_ih, W_hh, am);
  hipLaunchKernelGGL(k_prep_bias, dim3(4), dim3(256), 0, stream, b_ih, b_hh, bias);
  hipLaunchKernelGGL(k_prep_wq2, dim3(320), dim3(256), 0, stream, W_ih, W_hh, bias, am, wq, sbuf);
  hipLaunchKernelGGL(k_prep_xq2, dim3(16384), dim3(256), 0, stream, x, am, xqd);
  hipLaunchKernelGGL(k_prep_afc, dim3(272), dim3(256), 0, stream, W_afc1, W_aout, wafc1b, waoutb);
  hipLaunchKernelGGL(k_prep_wcb, dim3(64), dim3(288), 0, stream, W_cont, W_bin, wcbb);
  hipLaunchKernelGGL(k_scan16, dim3(64), dim3(512), 0, stream, wq, xqd, sbuf, hs);
  hipLaunchKernelGGL(k_act, dim3(8192), dim3(256), 0, stream, hs, wafc1b, waoutb, b_afc1, b_aout, outf + ACT_OFF);
  hipLaunchKernelGGL(k_cb, dim3(8192), dim3(256), 0, stream, hs, x, wcbb, b_cont, b_bin, outf);
}